// Round 4
// baseline (442.521 us; speedup 1.0000x reference)
//
#include <hip/hip_runtime.h>

typedef __bf16 bf16x8 __attribute__((ext_vector_type(8)));
typedef float f32x4 __attribute__((ext_vector_type(4)));

#define EMB 1024
#define CTXD 768
#define NH 16
#define HD 64
#define BB 8
#define NN 4096
#define MM 77
#define MPAD 96

static __device__ __forceinline__ unsigned short f2bf(float f) {
    unsigned u = __builtin_bit_cast(unsigned, f);
    u += 0x7FFFu + ((u >> 16) & 1u);
    return (unsigned short)(u >> 16);
}

// ---------------- mask layout detection + lengths ----------------
__global__ void mask_lengths_kernel(const unsigned char* __restrict__ mask,
                                    int* __restrict__ lengths) {
    __shared__ int layout; // 0=int32, 1=byte(bool), 2=float32
    if (threadIdx.x == 0) {
        int anyOdd = 0, anyF = 0;
        for (int i = 0; i < BB * MM; ++i) {
            unsigned char v = mask[i];
            if (v == 0x80u || v == 0x3Fu) anyF = 1;
            if ((i & 3) && v) anyOdd = 1;
        }
        layout = anyF ? 2 : (anyOdd ? 1 : 0);
    }
    __syncthreads();
    if (threadIdx.x < BB) {
        int b = threadIdx.x, cnt = 0, lay = layout;
        for (int m = 0; m < MM; ++m) {
            int idx = b * MM + m;
            int valid;
            if (lay == 1)      valid = mask[idx] != 0;
            else if (lay == 0) valid = ((const int*)mask)[idx] != 0;
            else               valid = ((const float*)mask)[idx] != 0.0f;
            cnt += valid ? 1 : 0;
        }
        lengths[b] = cnt;
    }
}

// ---------------- fp32 -> bf16 cast (8 elems/thread) ----------------
__global__ void cast_f32_to_bf16(const float* __restrict__ in,
                                 unsigned short* __restrict__ out, int n8) {
    for (int i = blockIdx.x * blockDim.x + threadIdx.x; i < n8;
         i += gridDim.x * blockDim.x) {
        float4 v0 = ((const float4*)in)[2 * i];
        float4 v1 = ((const float4*)in)[2 * i + 1];
        union { unsigned short u[8]; int4 v; } r;
        r.u[0] = f2bf(v0.x); r.u[1] = f2bf(v0.y);
        r.u[2] = f2bf(v0.z); r.u[3] = f2bf(v0.w);
        r.u[4] = f2bf(v1.x); r.u[5] = f2bf(v1.y);
        r.u[6] = f2bf(v1.z); r.u[7] = f2bf(v1.w);
        ((int4*)out)[i] = r.v;
    }
}

// ---------------- context cast with zero pad to 640 rows ----------------
__global__ void cast_ctx_kernel(const float* __restrict__ in,
                                unsigned short* __restrict__ out) {
    int i = blockIdx.x * 256 + threadIdx.x; // over 640*768/8 chunks
    if (i >= 640 * CTXD / 8) return;
    int e0 = i * 8;
    int row = e0 / CTXD;
    union { unsigned short u[8]; int4 v; } r;
    if (row < BB * MM) {
        float4 v0 = ((const float4*)in)[2 * i];
        float4 v1 = ((const float4*)in)[2 * i + 1];
        r.u[0] = f2bf(v0.x); r.u[1] = f2bf(v0.y);
        r.u[2] = f2bf(v0.z); r.u[3] = f2bf(v0.w);
        r.u[4] = f2bf(v1.x); r.u[5] = f2bf(v1.y);
        r.u[6] = f2bf(v1.z); r.u[7] = f2bf(v1.w);
    } else {
        r.v = make_int4(0, 0, 0, 0);
    }
    ((int4*)out)[i] = r.v;
}

// ---------------- transpose + cast: W (R x C fp32) -> Wt (C x R bf16) -----
__global__ void transpose_cast_kernel(const float* __restrict__ W,
                                      unsigned short* __restrict__ Wt,
                                      int R, int C) {
    __shared__ float t[32][33];
    int tx = threadIdx.x, ty = threadIdx.y;
    int c0 = blockIdx.x * 32, r0 = blockIdx.y * 32;
#pragma unroll
    for (int i = 0; i < 32; i += 8)
        t[ty + i][tx] = W[(size_t)(r0 + ty + i) * C + c0 + tx];
    __syncthreads();
#pragma unroll
    for (int i = 0; i < 32; i += 8)
        Wt[(size_t)(c0 + ty + i) * R + r0 + tx] = f2bf(t[tx][ty + i]);
}

// ---------------- 128x128 bf16 GEMM (m97 structure) ----------------
// A: M x K row-major bf16, Bt: N x K row-major bf16 (i.e. B transposed)
// N is the FAST grid axis: 8 consecutive wgs (one XCD chunk) share one
// A-panel -> A fetched ~once instead of numN times.
static __device__ __forceinline__ void stage_tile(
    const unsigned short* __restrict__ G, int ldg, unsigned short* lds,
    int r0, int kt, int wv, int ln) {
    int rown = ln >> 2;
    int koff = (ln & 3) * 8;
#pragma unroll
    for (int r = 0; r < 2; ++r) {
        int cw = wv * 2 + r;
        const unsigned short* src =
            G + (size_t)(r0 + cw * 16 + rown) * ldg + kt + koff;
        __builtin_amdgcn_global_load_lds(
            (const __attribute__((address_space(1))) void*)src,
            (__attribute__((address_space(3))) void*)(lds + cw * 512),
            16, 0, 0);
    }
}

template <int MODE>
__global__ __launch_bounds__(256) void gemm_bt_kernel(
    const unsigned short* __restrict__ A, const unsigned short* __restrict__ Bt,
    const float* __restrict__ bias, void* __restrict__ Cout,
    int M, int N, int K) {
    __shared__ unsigned short As[128 * 32];
    __shared__ unsigned short Bs[128 * 32];
    const int tid = threadIdx.x, wv = tid >> 6, ln = tid & 63;
    const int numM = M >> 7, numN = N >> 7;
    int bid = blockIdx.x;
    const int nwg = numM * numN;
    if ((nwg & 7) == 0) { int cpx = nwg >> 3; bid = (bid & 7) * cpx + (bid >> 3); }
    const int nt = bid % numN, mt = bid / numN;   // N fast
    const int m0 = mt << 7, n0 = nt << 7;
    const int wr = wv >> 1, wc = wv & 1;

    f32x4 acc[4][4] = {};
    for (int kt = 0; kt < K; kt += 32) {
        __syncthreads();
        stage_tile(A, K, As, m0, kt, wv, ln);
        stage_tile(Bt, K, Bs, n0, kt, wv, ln);
        __syncthreads();
        bf16x8 af[4], bfr[4];
#pragma unroll
        for (int i = 0; i < 4; ++i)
            af[i] = *(const bf16x8*)(As + (wr * 64 + i * 16 + (ln & 15)) * 32 +
                                     (ln >> 4) * 8);
#pragma unroll
        for (int j = 0; j < 4; ++j)
            bfr[j] = *(const bf16x8*)(Bs + (wc * 64 + j * 16 + (ln & 15)) * 32 +
                                      (ln >> 4) * 8);
#pragma unroll
        for (int i = 0; i < 4; ++i)
#pragma unroll
            for (int j = 0; j < 4; ++j)
                acc[i][j] = __builtin_amdgcn_mfma_f32_16x16x32_bf16(
                    af[i], bfr[j], acc[i][j], 0, 0, 0);
    }

    float bvals[4];
#pragma unroll
    for (int j = 0; j < 4; ++j)
        bvals[j] = bias[n0 + wc * 64 + j * 16 + (ln & 15)];

#pragma unroll
    for (int i = 0; i < 4; ++i) {
#pragma unroll
        for (int j = 0; j < 4; ++j) {
#pragma unroll
            for (int r = 0; r < 4; ++r) {
                int row = m0 + wr * 64 + i * 16 + (ln >> 4) * 4 + r;
                int col = n0 + wc * 64 + j * 16 + (ln & 15);
                float v = acc[i][j][r] + bvals[j];
                if constexpr (MODE == 0) {
                    ((unsigned short*)Cout)[(size_t)row * N + col] = f2bf(v);
                } else if constexpr (MODE == 1) {
                    ((float*)Cout)[(size_t)row * N + col] = v;
                } else {
                    if (row < BB * MM) {
                        int bb = row / MM, m = row - bb * MM;
                        int hh = col >> 6, d = col & 63;
                        if constexpr (MODE == 2)
                            ((unsigned short*)Cout)[((size_t)(bb * NH + hh) * MPAD + m) * HD + d] = f2bf(v);
                        else
                            ((unsigned short*)Cout)[((size_t)(bb * NH + hh) * HD + d) * MPAD + m] = f2bf(v);
                    }
                }
            }
        }
    }
}

// ---------------- fused attention: barrier-free, K/V direct from L2 -------
// One wg = 4 waves; each wave owns 16 q-rows of a (64 q-rows, head) tile.
// K/V per (b,h) is 24 KB, shared by 64 wgs -> L2-resident; no LDS staging.
__global__ __launch_bounds__(256) void attn_kernel(
    const unsigned short* __restrict__ Q, const unsigned short* __restrict__ Kw,
    const unsigned short* __restrict__ Vt, const int* __restrict__ lengths,
    unsigned short* __restrict__ Out) {
    const int bh = blockIdx.y;
    const int b = bh >> 4, h = bh & 15;
    const int q0 = blockIdx.x * 64;
    const int tid = threadIdx.x, wv = tid >> 6, ln = tid & 63;
    const int len = lengths[b];

    __shared__ unsigned short Ps[64][104]; // normalized P rows q, cols m

    const unsigned short* Ksrc = Kw + (size_t)bh * (MPAD * HD);
    const unsigned short* Vsrc = Vt + (size_t)bh * (HD * MPAD);

    // Q fragments straight from global (each element read exactly once)
    const int qr = q0 + wv * 16 + (ln & 15);
    const unsigned short* qptr =
        Q + (size_t)(b * NN + qr) * EMB + h * HD + (ln >> 4) * 8;
    bf16x8 aq0 = *(const bf16x8*)(qptr);
    bf16x8 aq1 = *(const bf16x8*)(qptr + 32);

    // S = Q K^T  (16 q-rows per wave x 96 cols), K fragments from global/L2
    f32x4 s[6] = {};
#pragma unroll
    for (int t = 0; t < 6; ++t) {
        const unsigned short* kp = Ksrc + (t * 16 + (ln & 15)) * HD + (ln >> 4) * 8;
        bf16x8 k0 = *(const bf16x8*)(kp);
        bf16x8 k1 = *(const bf16x8*)(kp + 32);
        s[t] = __builtin_amdgcn_mfma_f32_16x16x32_bf16(aq0, k0, s[t], 0, 0, 0);
        s[t] = __builtin_amdgcn_mfma_f32_16x16x32_bf16(aq1, k1, s[t], 0, 0, 0);
    }

    // masked softmax; S layout: row q=(ln>>4)*4+r, col m=t*16+(ln&15)
    const float scale = 0.125f;
    float mx[4] = {-1e30f, -1e30f, -1e30f, -1e30f};
#pragma unroll
    for (int t = 0; t < 6; ++t) {
        int m = t * 16 + (ln & 15);
#pragma unroll
        for (int r = 0; r < 4; ++r) {
            float v = (m < len) ? s[t][r] * scale : -1e30f;
            s[t][r] = v;
            mx[r] = fmaxf(mx[r], v);
        }
    }
#pragma unroll
    for (int d = 1; d < 16; d <<= 1)
#pragma unroll
        for (int r = 0; r < 4; ++r)
            mx[r] = fmaxf(mx[r], __shfl_xor(mx[r], d, 64));

    float sum[4] = {0.f, 0.f, 0.f, 0.f};
#pragma unroll
    for (int t = 0; t < 6; ++t)
#pragma unroll
        for (int r = 0; r < 4; ++r) {
            float p = __expf(s[t][r] - mx[r]);
            s[t][r] = p;
            sum[r] += p;
        }
#pragma unroll
    for (int d = 1; d < 16; d <<= 1)
#pragma unroll
        for (int r = 0; r < 4; ++r)
            sum[r] += __shfl_xor(sum[r], d, 64);

    float rinv[4];
#pragma unroll
    for (int r = 0; r < 4; ++r) rinv[r] = 1.0f / sum[r];

    // write NORMALIZED P (bf16) to LDS, own rows only.
    // Same-wave ds_write -> ds_read: DS pipe in-order, no barrier needed.
#pragma unroll
    for (int t = 0; t < 6; ++t)
#pragma unroll
        for (int r = 0; r < 4; ++r)
            Ps[wv * 16 + (ln >> 4) * 4 + r][t * 16 + (ln & 15)] =
                f2bf(s[t][r] * rinv[r]);

    // O^T = V P^T via swapped operands: o[j] = mfma(V_frag, P_frag).
    // Output: d = j*16 + (ln>>4)*4 + r  (4 consecutive d per lane!), q = ln&15.
    f32x4 o[4] = {};
#pragma unroll
    for (int ks = 0; ks < 3; ++ks) {
        bf16x8 pf = *(const bf16x8*)(&Ps[wv * 16 + (ln & 15)][ks * 32 + (ln >> 4) * 8]);
#pragma unroll
        for (int j = 0; j < 4; ++j) {
            bf16x8 vf = *(const bf16x8*)(Vsrc + (j * 16 + (ln & 15)) * MPAD +
                                         ks * 32 + (ln >> 4) * 8);
            o[j] = __builtin_amdgcn_mfma_f32_16x16x32_bf16(vf, pf, o[j], 0, 0, 0);
        }
    }

    // packed 8B stores: 4 consecutive d per lane
    const int qrow = q0 + wv * 16 + (ln & 15);
    unsigned short* obase = Out + (size_t)(b * NN + qrow) * EMB + h * HD + (ln >> 4) * 4;
#pragma unroll
    for (int j = 0; j < 4; ++j) {
        union { unsigned short u[4]; unsigned long long ll; } pk;
#pragma unroll
        for (int r = 0; r < 4; ++r) pk.u[r] = f2bf(o[j][r]);
        *(unsigned long long*)(obase + j * 16) = pk.ll;
    }
}

// ---------------- launch ----------------
extern "C" void kernel_launch(void* const* d_in, const int* in_sizes, int n_in,
                              void* d_out, int out_size, void* d_ws, size_t ws_size,
                              hipStream_t stream) {
    const float* x    = (const float*)d_in[0];
    const float* ctx  = (const float*)d_in[1];
    const unsigned char* cmask = (const unsigned char*)d_in[2];
    const float* Wq = (const float*)d_in[3];
    const float* bq = (const float*)d_in[4];
    const float* Wk = (const float*)d_in[5];
    const float* bk = (const float*)d_in[6];
    const float* Wv = (const float*)d_in[7];
    const float* bv = (const float*)d_in[8];
    const float* Wo = (const float*)d_in[9];
    const float* bo = (const float*)d_in[10];

    // ws layout (~75 MiB). Qb lives in d_out's front half (dead until the
    // final O-GEMM overwrites all of d_out, in stream order).
    char* ws = (char*)d_ws;
    unsigned short* Xbf   = (unsigned short*)(ws);              // 64 MiB; reused as attn_out
    unsigned short* Wq_t  = (unsigned short*)(ws + 67108864);   // 2 MiB
    unsigned short* Wo_t  = (unsigned short*)(ws + 69206016);   // 2 MiB
    unsigned short* Wk_t  = (unsigned short*)(ws + 71303168);   // 1.5 MiB
    unsigned short* Wv_t  = (unsigned short*)(ws + 72876032);   // 1.5 MiB
    unsigned short* Cbf   = (unsigned short*)(ws + 74448896);   // 640x768 bf16
    unsigned short* Kw    = (unsigned short*)(ws + 75431936);   // 128x96x64 bf16
    unsigned short* Vtw   = (unsigned short*)(ws + 77004800);   // 128x64x96 bf16
    int* lengths          = (int*)(ws + 78577664);
    unsigned short* Qb    = (unsigned short*)d_out;             // 64 MiB scratch

    mask_lengths_kernel<<<1, 64, 0, stream>>>(cmask, lengths);
    cast_f32_to_bf16<<<2048, 256, 0, stream>>>(x, Xbf, (BB * NN * EMB) / 8);
    cast_ctx_kernel<<<240, 256, 0, stream>>>(ctx, Cbf);
    transpose_cast_kernel<<<dim3(32, 32), dim3(32, 8), 0, stream>>>(Wq, Wq_t, 1024, 1024);
    transpose_cast_kernel<<<dim3(32, 24), dim3(32, 8), 0, stream>>>(Wk, Wk_t, 768, 1024);
    transpose_cast_kernel<<<dim3(32, 24), dim3(32, 8), 0, stream>>>(Wv, Wv_t, 768, 1024);
    transpose_cast_kernel<<<dim3(32, 32), dim3(32, 8), 0, stream>>>(Wo, Wo_t, 1024, 1024);
    hipMemsetAsync(Kw, 0, 2 * 1572864, stream); // zero K + V^T padded buffers

    gemm_bt_kernel<0><<<2048, 256, 0, stream>>>(Xbf, Wq_t, bq, Qb, 32768, 1024, 1024);
    gemm_bt_kernel<2><<<40, 256, 0, stream>>>(Cbf, Wk_t, bk, Kw, 640, 1024, 768);
    gemm_bt_kernel<3><<<40, 256, 0, stream>>>(Cbf, Wv_t, bv, Vtw, 640, 1024, 768);

    attn_kernel<<<dim3(64, 128), 256, 0, stream>>>(Qb, Kw, Vtw, lengths, Xbf);

    gemm_bt_kernel<1><<<2048, 256, 0, stream>>>(Xbf, Wo_t, bo, d_out, 32768, 1024, 1024);
}

// Round 5
// 409.259 us; speedup vs baseline: 1.0813x; 1.0813x over previous
//
#include <hip/hip_runtime.h>

typedef __bf16 bf16x8 __attribute__((ext_vector_type(8)));
typedef float f32x4 __attribute__((ext_vector_type(4)));

#define EMB 1024
#define CTXD 768
#define NH 16
#define HD 64
#define BB 8
#define NN 4096
#define MM 77
#define MPAD 96

static __device__ __forceinline__ unsigned short f2bf(float f) {
    unsigned u = __builtin_bit_cast(unsigned, f);
    u += 0x7FFFu + ((u >> 16) & 1u);
    return (unsigned short)(u >> 16);
}

// ---------------- mask layout detection + lengths ----------------
__global__ void mask_lengths_kernel(const unsigned char* __restrict__ mask,
                                    int* __restrict__ lengths) {
    __shared__ int layout; // 0=int32, 1=byte(bool), 2=float32
    if (threadIdx.x == 0) {
        int anyOdd = 0, anyF = 0;
        for (int i = 0; i < BB * MM; ++i) {
            unsigned char v = mask[i];
            if (v == 0x80u || v == 0x3Fu) anyF = 1;
            if ((i & 3) && v) anyOdd = 1;
        }
        layout = anyF ? 2 : (anyOdd ? 1 : 0);
    }
    __syncthreads();
    if (threadIdx.x < BB) {
        int b = threadIdx.x, cnt = 0, lay = layout;
        for (int m = 0; m < MM; ++m) {
            int idx = b * MM + m;
            int valid;
            if (lay == 1)      valid = mask[idx] != 0;
            else if (lay == 0) valid = ((const int*)mask)[idx] != 0;
            else               valid = ((const float*)mask)[idx] != 0.0f;
            cnt += valid ? 1 : 0;
        }
        lengths[b] = cnt;
    }
}

// ---------------- fp32 -> bf16 cast (8 elems/thread) ----------------
__global__ void cast_f32_to_bf16(const float* __restrict__ in,
                                 unsigned short* __restrict__ out, int n8) {
    for (int i = blockIdx.x * blockDim.x + threadIdx.x; i < n8;
         i += gridDim.x * blockDim.x) {
        float4 v0 = ((const float4*)in)[2 * i];
        float4 v1 = ((const float4*)in)[2 * i + 1];
        union { unsigned short u[8]; int4 v; } r;
        r.u[0] = f2bf(v0.x); r.u[1] = f2bf(v0.y);
        r.u[2] = f2bf(v0.z); r.u[3] = f2bf(v0.w);
        r.u[4] = f2bf(v1.x); r.u[5] = f2bf(v1.y);
        r.u[6] = f2bf(v1.z); r.u[7] = f2bf(v1.w);
        ((int4*)out)[i] = r.v;
    }
}

// ---------------- context cast with zero pad to 640 rows ----------------
__global__ void cast_ctx_kernel(const float* __restrict__ in,
                                unsigned short* __restrict__ out) {
    int i = blockIdx.x * 256 + threadIdx.x; // over 640*768/8 chunks
    if (i >= 640 * CTXD / 8) return;
    int e0 = i * 8;
    int row = e0 / CTXD;
    union { unsigned short u[8]; int4 v; } r;
    if (row < BB * MM) {
        float4 v0 = ((const float4*)in)[2 * i];
        float4 v1 = ((const float4*)in)[2 * i + 1];
        r.u[0] = f2bf(v0.x); r.u[1] = f2bf(v0.y);
        r.u[2] = f2bf(v0.z); r.u[3] = f2bf(v0.w);
        r.u[4] = f2bf(v1.x); r.u[5] = f2bf(v1.y);
        r.u[6] = f2bf(v1.z); r.u[7] = f2bf(v1.w);
    } else {
        r.v = make_int4(0, 0, 0, 0);
    }
    ((int4*)out)[i] = r.v;
}

// ---------------- transpose + cast: W (R x C fp32) -> Wt (C x R bf16) -----
__global__ void transpose_cast_kernel(const float* __restrict__ W,
                                      unsigned short* __restrict__ Wt,
                                      int R, int C) {
    __shared__ float t[32][33];
    int tx = threadIdx.x, ty = threadIdx.y;
    int c0 = blockIdx.x * 32, r0 = blockIdx.y * 32;
#pragma unroll
    for (int i = 0; i < 32; i += 8)
        t[ty + i][tx] = W[(size_t)(r0 + ty + i) * C + c0 + tx];
    __syncthreads();
#pragma unroll
    for (int i = 0; i < 32; i += 8)
        Wt[(size_t)(c0 + ty + i) * R + r0 + tx] = f2bf(t[tx][ty + i]);
}

// ============ 256x256 deep-pipelined GEMM (counted-vmcnt schedule) ========
// A: M x K row-major bf16, Bt: N x K row-major bf16.
// BK=32, 4 LDS buffers (128 KiB), prefetch distance 3 K-tiles, 8 waves
// (2M x 4N), per-wave C = 128x64 (acc 8x4 fragments). Two phases per
// K-tile, 16 MFMA per phase between raw s_barriers; vmcnt(8) once per
// tile (loads stay in flight across barriers — T3+T4). LDS chunk-swizzle
// slot = chunk ^ ((row>>1)&3) applied on BOTH the global source of
// global_load_lds (inverse) and the ds_read address -> 2-way (free).
// MODE 0: C bf16 +bias; MODE 1: C fp32 +bias.
template <int MODE>
__global__ __launch_bounds__(512, 2) void gemm256_kernel(
    const unsigned short* __restrict__ A, const unsigned short* __restrict__ Bt,
    const float* __restrict__ bias, void* __restrict__ Cout,
    int M, int N, int K) {
    __shared__ unsigned short lds[4][2][256 * 32]; // [buf][A/B][row*32+col]
    const int tid = threadIdx.x, wv = tid >> 6, ln = tid & 63;
    const int numN = N >> 8;
    int bid = blockIdx.x;
    const int nwg = (M >> 8) * numN;
    if ((nwg & 7) == 0) { int cpx = nwg >> 3; bid = (bid & 7) * cpx + (bid >> 3); }
    const int nt_ = bid % numN, mt = bid / numN;   // N fast
    const int m0 = mt << 8, n0 = nt_ << 8;
    const int wr = wv >> 2, wc = wv & 3;
    const int NT = K >> 5;

    // staging lane constants: each wave instr covers 16 rows (64 lanes x 16B)
    const int srow = wv * 16 + (ln >> 2); // row within a 128-row half
    const int sslot = ln & 3;             // LDS 16B slot within the 64B row

    f32x4 acc[8][4] = {};

    // ---- prologue: fully stage tiles 0,1,2 ----
#pragma unroll
    for (int t = 0; t < 3; ++t) {
#pragma unroll
        for (int half = 0; half < 2; ++half) {
            int row = half * 128 + srow;
            int gc = sslot ^ ((row >> 1) & 3);
            __builtin_amdgcn_global_load_lds(
                (const __attribute__((address_space(1))) void*)(
                    A + (size_t)(m0 + row) * K + (t << 5) + gc * 8),
                (__attribute__((address_space(3))) void*)(
                    &lds[t][0][(half * 128 + wv * 16) * 32]),
                16, 0, 0);
            __builtin_amdgcn_global_load_lds(
                (const __attribute__((address_space(1))) void*)(
                    Bt + (size_t)(n0 + row) * K + (t << 5) + gc * 8),
                (__attribute__((address_space(3))) void*)(
                    &lds[t][1][(half * 128 + wv * 16) * 32]),
                16, 0, 0);
        }
    }
    asm volatile("s_waitcnt vmcnt(8)" ::: "memory"); // tile 0 landed
    __builtin_amdgcn_sched_barrier(0);
    __builtin_amdgcn_s_barrier();

    for (int t = 0; t < NT; ++t) {
        const unsigned short* As = lds[t & 3][0];
        const unsigned short* Bs = lds[t & 3][1];
        const int kt3 = (t + 3) << 5;
        // ---- phase 0: stage A(t+3); B frags + A frags 0..3; MFMA ----
        if (t + 3 < NT) {
#pragma unroll
            for (int half = 0; half < 2; ++half) {
                int row = half * 128 + srow;
                int gc = sslot ^ ((row >> 1) & 3);
                __builtin_amdgcn_global_load_lds(
                    (const __attribute__((address_space(1))) void*)(
                        A + (size_t)(m0 + row) * K + kt3 + gc * 8),
                    (__attribute__((address_space(3))) void*)(
                        &lds[(t + 3) & 3][0][(half * 128 + wv * 16) * 32]),
                    16, 0, 0);
            }
        }
        bf16x8 bfr[4], af[4];
#pragma unroll
        for (int j = 0; j < 4; ++j) {
            int brow = wc * 64 + j * 16 + (ln & 15);
            int bslot = (ln >> 4) ^ ((brow >> 1) & 3);
            bfr[j] = *(const bf16x8*)(Bs + brow * 32 + bslot * 8);
        }
#pragma unroll
        for (int i = 0; i < 4; ++i) {
            int arow = wr * 128 + i * 16 + (ln & 15);
            int aslot = (ln >> 4) ^ ((arow >> 1) & 3);
            af[i] = *(const bf16x8*)(As + arow * 32 + aslot * 8);
        }
        __builtin_amdgcn_s_barrier();
        __builtin_amdgcn_s_setprio(1);
#pragma unroll
        for (int i = 0; i < 4; ++i)
#pragma unroll
            for (int j = 0; j < 4; ++j)
                acc[i][j] = __builtin_amdgcn_mfma_f32_16x16x32_bf16(
                    af[i], bfr[j], acc[i][j], 0, 0, 0);
        __builtin_amdgcn_s_setprio(0);
        __builtin_amdgcn_s_barrier();
        // ---- phase 1: stage B(t+3); A frags 4..7; MFMA ----
        if (t + 3 < NT) {
#pragma unroll
            for (int half = 0; half < 2; ++half) {
                int row = half * 128 + srow;
                int gc = sslot ^ ((row >> 1) & 3);
                __builtin_amdgcn_global_load_lds(
                    (const __attribute__((address_space(1))) void*)(
                        Bt + (size_t)(n0 + row) * K + kt3 + gc * 8),
                    (__attribute__((address_space(3))) void*)(
                        &lds[(t + 3) & 3][1][(half * 128 + wv * 16) * 32]),
                    16, 0, 0);
            }
        }
#pragma unroll
        for (int i = 0; i < 4; ++i) {
            int arow = wr * 128 + (i + 4) * 16 + (ln & 15);
            int aslot = (ln >> 4) ^ ((arow >> 1) & 3);
            af[i] = *(const bf16x8*)(As + arow * 32 + aslot * 8);
        }
        __builtin_amdgcn_s_barrier();
        __builtin_amdgcn_s_setprio(1);
#pragma unroll
        for (int i = 0; i < 4; ++i)
#pragma unroll
            for (int j = 0; j < 4; ++j)
                acc[i + 4][j] = __builtin_amdgcn_mfma_f32_16x16x32_bf16(
                    af[i], bfr[j], acc[i + 4][j], 0, 0, 0);
        __builtin_amdgcn_s_setprio(0);
        // ---- tile boundary: wait for tile t+1's staging (counted) ----
        if (t < NT - 1) {
            if (t + 3 < NT)      { asm volatile("s_waitcnt vmcnt(8)" ::: "memory"); }
            else if (t + 2 < NT) { asm volatile("s_waitcnt vmcnt(4)" ::: "memory"); }
            else                 { asm volatile("s_waitcnt vmcnt(0)" ::: "memory"); }
            __builtin_amdgcn_sched_barrier(0);
        }
        __builtin_amdgcn_s_barrier();
    }

    // ---- epilogue ----
    float bvals[4];
#pragma unroll
    for (int j = 0; j < 4; ++j)
        bvals[j] = bias[n0 + wc * 64 + j * 16 + (ln & 15)];
#pragma unroll
    for (int i = 0; i < 8; ++i)
#pragma unroll
        for (int j = 0; j < 4; ++j)
#pragma unroll
            for (int r = 0; r < 4; ++r) {
                int row = m0 + wr * 128 + i * 16 + (ln >> 4) * 4 + r;
                int col = n0 + wc * 64 + j * 16 + (ln & 15);
                float v = acc[i][j][r] + bvals[j];
                if constexpr (MODE == 0)
                    ((unsigned short*)Cout)[(size_t)row * N + col] = f2bf(v);
                else
                    ((float*)Cout)[(size_t)row * N + col] = v;
            }
}

// ---------------- 128x128 bf16 GEMM (m97 structure) — K/V scatter only ----
// MODE 2: K scatter: row->(b,m), col->(h,d): out[((b*16+h)*96+m)*64+d] bf16
// MODE 3: V scatter transposed: out[((b*16+h)*64+d)*96+m] bf16
static __device__ __forceinline__ void stage_tile(
    const unsigned short* __restrict__ G, int ldg, unsigned short* lds,
    int r0, int kt, int wv, int ln) {
    int rown = ln >> 2;
    int koff = (ln & 3) * 8;
#pragma unroll
    for (int r = 0; r < 2; ++r) {
        int cw = wv * 2 + r;
        const unsigned short* src =
            G + (size_t)(r0 + cw * 16 + rown) * ldg + kt + koff;
        __builtin_amdgcn_global_load_lds(
            (const __attribute__((address_space(1))) void*)src,
            (__attribute__((address_space(3))) void*)(lds + cw * 512),
            16, 0, 0);
    }
}

template <int MODE>
__global__ __launch_bounds__(256) void gemm_bt_kernel(
    const unsigned short* __restrict__ A, const unsigned short* __restrict__ Bt,
    const float* __restrict__ bias, void* __restrict__ Cout,
    int M, int N, int K) {
    __shared__ unsigned short As[128 * 32];
    __shared__ unsigned short Bs[128 * 32];
    const int tid = threadIdx.x, wv = tid >> 6, ln = tid & 63;
    const int numM = M >> 7, numN = N >> 7;
    int bid = blockIdx.x;
    const int nwg = numM * numN;
    if ((nwg & 7) == 0) { int cpx = nwg >> 3; bid = (bid & 7) * cpx + (bid >> 3); }
    const int nt = bid % numN, mt = bid / numN;   // N fast
    const int m0 = mt << 7, n0 = nt << 7;
    const int wr = wv >> 1, wc = wv & 1;

    f32x4 acc[4][4] = {};
    for (int kt = 0; kt < K; kt += 32) {
        __syncthreads();
        stage_tile(A, K, As, m0, kt, wv, ln);
        stage_tile(Bt, K, Bs, n0, kt, wv, ln);
        __syncthreads();
        bf16x8 af[4], bfr[4];
#pragma unroll
        for (int i = 0; i < 4; ++i)
            af[i] = *(const bf16x8*)(As + (wr * 64 + i * 16 + (ln & 15)) * 32 +
                                     (ln >> 4) * 8);
#pragma unroll
        for (int j = 0; j < 4; ++j)
            bfr[j] = *(const bf16x8*)(Bs + (wc * 64 + j * 16 + (ln & 15)) * 32 +
                                      (ln >> 4) * 8);
#pragma unroll
        for (int i = 0; i < 4; ++i)
#pragma unroll
            for (int j = 0; j < 4; ++j)
                acc[i][j] = __builtin_amdgcn_mfma_f32_16x16x32_bf16(
                    af[i], bfr[j], acc[i][j], 0, 0, 0);
    }

    float bvals[4];
#pragma unroll
    for (int j = 0; j < 4; ++j)
        bvals[j] = bias[n0 + wc * 64 + j * 16 + (ln & 15)];

#pragma unroll
    for (int i = 0; i < 4; ++i) {
#pragma unroll
        for (int j = 0; j < 4; ++j) {
#pragma unroll
            for (int r = 0; r < 4; ++r) {
                int row = m0 + wr * 64 + i * 16 + (ln >> 4) * 4 + r;
                int col = n0 + wc * 64 + j * 16 + (ln & 15);
                float v = acc[i][j][r] + bvals[j];
                if (row < BB * MM) {
                    int bb = row / MM, m = row - bb * MM;
                    int hh = col >> 6, d = col & 63;
                    if constexpr (MODE == 2)
                        ((unsigned short*)Cout)[((size_t)(bb * NH + hh) * MPAD + m) * HD + d] = f2bf(v);
                    else
                        ((unsigned short*)Cout)[((size_t)(bb * NH + hh) * HD + d) * MPAD + m] = f2bf(v);
                }
            }
        }
    }
}

// ---------------- fused attention: barrier-free, K/V direct from L2 -------
__global__ __launch_bounds__(256) void attn_kernel(
    const unsigned short* __restrict__ Q, const unsigned short* __restrict__ Kw,
    const unsigned short* __restrict__ Vt, const int* __restrict__ lengths,
    unsigned short* __restrict__ Out) {
    const int bh = blockIdx.y;
    const int b = bh >> 4, h = bh & 15;
    const int q0 = blockIdx.x * 64;
    const int tid = threadIdx.x, wv = tid >> 6, ln = tid & 63;
    const int len = lengths[b];

    __shared__ unsigned short Ps[64][104]; // normalized P rows q, cols m

    const unsigned short* Ksrc = Kw + (size_t)bh * (MPAD * HD);
    const unsigned short* Vsrc = Vt + (size_t)bh * (HD * MPAD);

    const int qr = q0 + wv * 16 + (ln & 15);
    const unsigned short* qptr =
        Q + (size_t)(b * NN + qr) * EMB + h * HD + (ln >> 4) * 8;
    bf16x8 aq0 = *(const bf16x8*)(qptr);
    bf16x8 aq1 = *(const bf16x8*)(qptr + 32);

    f32x4 s[6] = {};
#pragma unroll
    for (int t = 0; t < 6; ++t) {
        const unsigned short* kp = Ksrc + (t * 16 + (ln & 15)) * HD + (ln >> 4) * 8;
        bf16x8 k0 = *(const bf16x8*)(kp);
        bf16x8 k1 = *(const bf16x8*)(kp + 32);
        s[t] = __builtin_amdgcn_mfma_f32_16x16x32_bf16(aq0, k0, s[t], 0, 0, 0);
        s[t] = __builtin_amdgcn_mfma_f32_16x16x32_bf16(aq1, k1, s[t], 0, 0, 0);
    }

    const float scale = 0.125f;
    float mx[4] = {-1e30f, -1e30f, -1e30f, -1e30f};
#pragma unroll
    for (int t = 0; t < 6; ++t) {
        int m = t * 16 + (ln & 15);
#pragma unroll
        for (int r = 0; r < 4; ++r) {
            float v = (m < len) ? s[t][r] * scale : -1e30f;
            s[t][r] = v;
            mx[r] = fmaxf(mx[r], v);
        }
    }
#pragma unroll
    for (int d = 1; d < 16; d <<= 1)
#pragma unroll
        for (int r = 0; r < 4; ++r)
            mx[r] = fmaxf(mx[r], __shfl_xor(mx[r], d, 64));

    float sum[4] = {0.f, 0.f, 0.f, 0.f};
#pragma unroll
    for (int t = 0; t < 6; ++t)
#pragma unroll
        for (int r = 0; r < 4; ++r) {
            float p = __expf(s[t][r] - mx[r]);
            s[t][r] = p;
            sum[r] += p;
        }
#pragma unroll
    for (int d = 1; d < 16; d <<= 1)
#pragma unroll
        for (int r = 0; r < 4; ++r)
            sum[r] += __shfl_xor(sum[r], d, 64);

    float rinv[4];
#pragma unroll
    for (int r = 0; r < 4; ++r) rinv[r] = 1.0f / sum[r];

#pragma unroll
    for (int t = 0; t < 6; ++t)
#pragma unroll
        for (int r = 0; r < 4; ++r)
            Ps[wv * 16 + (ln >> 4) * 4 + r][t * 16 + (ln & 15)] =
                f2bf(s[t][r] * rinv[r]);

    f32x4 o[4] = {};
#pragma unroll
    for (int ks = 0; ks < 3; ++ks) {
        bf16x8 pf = *(const bf16x8*)(&Ps[wv * 16 + (ln & 15)][ks * 32 + (ln >> 4) * 8]);
#pragma unroll
        for (int j = 0; j < 4; ++j) {
            bf16x8 vf = *(const bf16x8*)(Vsrc + (j * 16 + (ln & 15)) * MPAD +
                                         ks * 32 + (ln >> 4) * 8);
            o[j] = __builtin_amdgcn_mfma_f32_16x16x32_bf16(vf, pf, o[j], 0, 0, 0);
        }
    }

    const int qrow = q0 + wv * 16 + (ln & 15);
    unsigned short* obase = Out + (size_t)(b * NN + qrow) * EMB + h * HD + (ln >> 4) * 4;
#pragma unroll
    for (int j = 0; j < 4; ++j) {
        union { unsigned short u[4]; unsigned long long ll; } pk;
#pragma unroll
        for (int r = 0; r < 4; ++r) pk.u[r] = f2bf(o[j][r]);
        *(unsigned long long*)(obase + j * 16) = pk.ll;
    }
}

// ---------------- launch ----------------
extern "C" void kernel_launch(void* const* d_in, const int* in_sizes, int n_in,
                              void* d_out, int out_size, void* d_ws, size_t ws_size,
                              hipStream_t stream) {
    const float* x    = (const float*)d_in[0];
    const float* ctx  = (const float*)d_in[1];
    const unsigned char* cmask = (const unsigned char*)d_in[2];
    const float* Wq = (const float*)d_in[3];
    const float* bq = (const float*)d_in[4];
    const float* Wk = (const float*)d_in[5];
    const float* bk = (const float*)d_in[6];
    const float* Wv = (const float*)d_in[7];
    const float* bv = (const float*)d_in[8];
    const float* Wo = (const float*)d_in[9];
    const float* bo = (const float*)d_in[10];

    char* ws = (char*)d_ws;
    unsigned short* Xbf   = (unsigned short*)(ws);              // 64 MiB; reused as attn_out
    unsigned short* Wq_t  = (unsigned short*)(ws + 67108864);   // 2 MiB
    unsigned short* Wo_t  = (unsigned short*)(ws + 69206016);   // 2 MiB
    unsigned short* Wk_t  = (unsigned short*)(ws + 71303168);   // 1.5 MiB
    unsigned short* Wv_t  = (unsigned short*)(ws + 72876032);   // 1.5 MiB
    unsigned short* Cbf   = (unsigned short*)(ws + 74448896);   // 640x768 bf16
    unsigned short* Kw    = (unsigned short*)(ws + 75431936);   // 128x96x64 bf16
    unsigned short* Vtw   = (unsigned short*)(ws + 77004800);   // 128x64x96 bf16
    int* lengths          = (int*)(ws + 78577664);
    unsigned short* Qb    = (unsigned short*)d_out;             // 64 MiB scratch

    mask_lengths_kernel<<<1, 64, 0, stream>>>(cmask, lengths);
    cast_f32_to_bf16<<<2048, 256, 0, stream>>>(x, Xbf, (BB * NN * EMB) / 8);
    cast_ctx_kernel<<<240, 256, 0, stream>>>(ctx, Cbf);
    transpose_cast_kernel<<<dim3(32, 32), dim3(32, 8), 0, stream>>>(Wq, Wq_t, 1024, 1024);
    transpose_cast_kernel<<<dim3(32, 24), dim3(32, 8), 0, stream>>>(Wk, Wk_t, 768, 1024);
    transpose_cast_kernel<<<dim3(32, 24), dim3(32, 8), 0, stream>>>(Wv, Wv_t, 768, 1024);
    transpose_cast_kernel<<<dim3(32, 32), dim3(32, 8), 0, stream>>>(Wo, Wo_t, 1024, 1024);
    hipMemsetAsync(Kw, 0, 2 * 1572864, stream); // zero K + V^T padded buffers

    gemm256_kernel<0><<<512, 512, 0, stream>>>(Xbf, Wq_t, bq, Qb, 32768, 1024, 1024);
    gemm_bt_kernel<2><<<40, 256, 0, stream>>>(Cbf, Wk_t, bk, Kw, 640, 1024, 768);
    gemm_bt_kernel<3><<<40, 256, 0, stream>>>(Cbf, Wv_t, bv, Vtw, 640, 1024, 768);

    attn_kernel<<<dim3(64, 128), 256, 0, stream>>>(Qb, Kw, Vtw, lengths, Xbf);

    gemm256_kernel<1><<<512, 512, 0, stream>>>(Xbf, Wo_t, bo, d_out, 32768, 1024, 1024);
}

// Round 6
// 319.390 us; speedup vs baseline: 1.3855x; 1.2814x over previous
//
#include <hip/hip_runtime.h>

typedef __bf16 bf16x8 __attribute__((ext_vector_type(8)));
typedef float f32x4 __attribute__((ext_vector_type(4)));

#define EMB 1024
#define CTXD 768
#define NH 16
#define HD 64
#define BB 8
#define NN 4096
#define MM 77
#define MPAD 96

static __device__ __forceinline__ unsigned short f2bf(float f) {
    unsigned u = __builtin_bit_cast(unsigned, f);
    u += 0x7FFFu + ((u >> 16) & 1u);
    return (unsigned short)(u >> 16);
}

// ---------------- mask layout detection + lengths (wave-parallel) --------
__global__ void mask_lengths_kernel(const unsigned char* __restrict__ mask,
                                    int* __restrict__ lengths) {
    int ln = threadIdx.x & 63;
    int anyOdd = 0, anyF = 0;
    for (int i = ln; i < BB * MM; i += 64) {
        unsigned char v = mask[i];
        if (v == 0x80u || v == 0x3Fu) anyF = 1;
        if ((i & 3) && v) anyOdd = 1;
    }
    anyF = __any(anyF); anyOdd = __any(anyOdd);
    int layout = anyF ? 2 : (anyOdd ? 1 : 0); // 0=int32 1=byte 2=float32
    int b = ln >> 3, j = ln & 7, cnt = 0;
    for (int m = j; m < MM; m += 8) {
        int idx = b * MM + m;
        int valid;
        if (layout == 1)      valid = mask[idx] != 0;
        else if (layout == 0) valid = ((const int*)mask)[idx] != 0;
        else                  valid = ((const float*)mask)[idx] != 0.0f;
        cnt += valid ? 1 : 0;
    }
    cnt += __shfl_xor(cnt, 1, 64);
    cnt += __shfl_xor(cnt, 2, 64);
    cnt += __shfl_xor(cnt, 4, 64);
    if (j == 0) lengths[b] = cnt;
}

// ---------------- fp32 -> bf16 cast (8 elems/thread) ----------------
__global__ void cast_f32_to_bf16(const float* __restrict__ in,
                                 unsigned short* __restrict__ out, int n8) {
    for (int i = blockIdx.x * blockDim.x + threadIdx.x; i < n8;
         i += gridDim.x * blockDim.x) {
        float4 v0 = ((const float4*)in)[2 * i];
        float4 v1 = ((const float4*)in)[2 * i + 1];
        union { unsigned short u[8]; int4 v; } r;
        r.u[0] = f2bf(v0.x); r.u[1] = f2bf(v0.y);
        r.u[2] = f2bf(v0.z); r.u[3] = f2bf(v0.w);
        r.u[4] = f2bf(v1.x); r.u[5] = f2bf(v1.y);
        r.u[6] = f2bf(v1.z); r.u[7] = f2bf(v1.w);
        ((int4*)out)[i] = r.v;
    }
}

// ---------------- context cast with zero pad to 640 rows ----------------
__global__ void cast_ctx_kernel(const float* __restrict__ in,
                                unsigned short* __restrict__ out) {
    int i = blockIdx.x * 256 + threadIdx.x;
    if (i >= 640 * CTXD / 8) return;
    int row = (i * 8) / CTXD;
    union { unsigned short u[8]; int4 v; } r;
    if (row < BB * MM) {
        float4 v0 = ((const float4*)in)[2 * i];
        float4 v1 = ((const float4*)in)[2 * i + 1];
        r.u[0] = f2bf(v0.x); r.u[1] = f2bf(v0.y);
        r.u[2] = f2bf(v0.z); r.u[3] = f2bf(v0.w);
        r.u[4] = f2bf(v1.x); r.u[5] = f2bf(v1.y);
        r.u[6] = f2bf(v1.z); r.u[7] = f2bf(v1.w);
    } else {
        r.v = make_int4(0, 0, 0, 0);
    }
    ((int4*)out)[i] = r.v;
}

// ------- merged transpose+cast for 4 weights: W (R x C) -> Wt (C x R) -----
struct TPtrs { const float* src[4]; unsigned short* dst[4]; };
__global__ void transpose4_kernel(TPtrs tp) {
    __shared__ float t[32][33];
    int z = blockIdx.z;
    int R = (z < 2) ? 1024 : 768, C = 1024;
    int r0 = blockIdx.y * 32;
    if (r0 >= R) return;
    const float* W = tp.src[z];
    unsigned short* Wt = tp.dst[z];
    int tx = threadIdx.x, ty = threadIdx.y;
    int c0 = blockIdx.x * 32;
#pragma unroll
    for (int i = 0; i < 32; i += 8)
        t[ty + i][tx] = W[(size_t)(r0 + ty + i) * C + c0 + tx];
    __syncthreads();
#pragma unroll
    for (int i = 0; i < 32; i += 8)
        Wt[(size_t)(c0 + ty + i) * R + r0 + tx] = f2bf(t[tx][ty + i]);
}

// ============ 256x256 deep-pipelined GEMM (counted-vmcnt schedule) ========
template <int MODE>
__global__ __launch_bounds__(512, 2) void gemm256_kernel(
    const unsigned short* __restrict__ A, const unsigned short* __restrict__ Bt,
    const float* __restrict__ bias, void* __restrict__ Cout,
    int M, int N, int K) {
    __shared__ unsigned short lds[4][2][256 * 32];
    const int tid = threadIdx.x, wv = tid >> 6, ln = tid & 63;
    const int numN = N >> 8;
    int bid = blockIdx.x;
    const int nwg = (M >> 8) * numN;
    if ((nwg & 7) == 0) { int cpx = nwg >> 3; bid = (bid & 7) * cpx + (bid >> 3); }
    const int nt_ = bid % numN, mt = bid / numN;
    const int m0 = mt << 8, n0 = nt_ << 8;
    const int wr = wv >> 2, wc = wv & 3;
    const int NT = K >> 5;

    const int srow = wv * 16 + (ln >> 2);
    const int sslot = ln & 3;

    f32x4 acc[8][4] = {};

#pragma unroll
    for (int t = 0; t < 3; ++t) {
#pragma unroll
        for (int half = 0; half < 2; ++half) {
            int row = half * 128 + srow;
            int gc = sslot ^ ((row >> 1) & 3);
            __builtin_amdgcn_global_load_lds(
                (const __attribute__((address_space(1))) void*)(
                    A + (size_t)(m0 + row) * K + (t << 5) + gc * 8),
                (__attribute__((address_space(3))) void*)(
                    &lds[t][0][(half * 128 + wv * 16) * 32]),
                16, 0, 0);
            __builtin_amdgcn_global_load_lds(
                (const __attribute__((address_space(1))) void*)(
                    Bt + (size_t)(n0 + row) * K + (t << 5) + gc * 8),
                (__attribute__((address_space(3))) void*)(
                    &lds[t][1][(half * 128 + wv * 16) * 32]),
                16, 0, 0);
        }
    }
    asm volatile("s_waitcnt vmcnt(8)" ::: "memory");
    __builtin_amdgcn_sched_barrier(0);
    __builtin_amdgcn_s_barrier();

    for (int t = 0; t < NT; ++t) {
        const unsigned short* As = lds[t & 3][0];
        const unsigned short* Bs = lds[t & 3][1];
        const int kt3 = (t + 3) << 5;
        if (t + 3 < NT) {
#pragma unroll
            for (int half = 0; half < 2; ++half) {
                int row = half * 128 + srow;
                int gc = sslot ^ ((row >> 1) & 3);
                __builtin_amdgcn_global_load_lds(
                    (const __attribute__((address_space(1))) void*)(
                        A + (size_t)(m0 + row) * K + kt3 + gc * 8),
                    (__attribute__((address_space(3))) void*)(
                        &lds[(t + 3) & 3][0][(half * 128 + wv * 16) * 32]),
                    16, 0, 0);
            }
        }
        bf16x8 bfr[4], af[4];
#pragma unroll
        for (int j = 0; j < 4; ++j) {
            int brow = wc * 64 + j * 16 + (ln & 15);
            int bslot = (ln >> 4) ^ ((brow >> 1) & 3);
            bfr[j] = *(const bf16x8*)(Bs + brow * 32 + bslot * 8);
        }
#pragma unroll
        for (int i = 0; i < 4; ++i) {
            int arow = wr * 128 + i * 16 + (ln & 15);
            int aslot = (ln >> 4) ^ ((arow >> 1) & 3);
            af[i] = *(const bf16x8*)(As + arow * 32 + aslot * 8);
        }
        __builtin_amdgcn_s_barrier();
        __builtin_amdgcn_s_setprio(1);
#pragma unroll
        for (int i = 0; i < 4; ++i)
#pragma unroll
            for (int j = 0; j < 4; ++j)
                acc[i][j] = __builtin_amdgcn_mfma_f32_16x16x32_bf16(
                    af[i], bfr[j], acc[i][j], 0, 0, 0);
        __builtin_amdgcn_s_setprio(0);
        __builtin_amdgcn_s_barrier();
        if (t + 3 < NT) {
#pragma unroll
            for (int half = 0; half < 2; ++half) {
                int row = half * 128 + srow;
                int gc = sslot ^ ((row >> 1) & 3);
                __builtin_amdgcn_global_load_lds(
                    (const __attribute__((address_space(1))) void*)(
                        Bt + (size_t)(n0 + row) * K + kt3 + gc * 8),
                    (__attribute__((address_space(3))) void*)(
                        &lds[(t + 3) & 3][1][(half * 128 + wv * 16) * 32]),
                    16, 0, 0);
            }
        }
#pragma unroll
        for (int i = 0; i < 4; ++i) {
            int arow = wr * 128 + (i + 4) * 16 + (ln & 15);
            int aslot = (ln >> 4) ^ ((arow >> 1) & 3);
            af[i] = *(const bf16x8*)(As + arow * 32 + aslot * 8);
        }
        __builtin_amdgcn_s_barrier();
        __builtin_amdgcn_s_setprio(1);
#pragma unroll
        for (int i = 0; i < 4; ++i)
#pragma unroll
            for (int j = 0; j < 4; ++j)
                acc[i + 4][j] = __builtin_amdgcn_mfma_f32_16x16x32_bf16(
                    af[i], bfr[j], acc[i + 4][j], 0, 0, 0);
        __builtin_amdgcn_s_setprio(0);
        if (t < NT - 1) {
            if (t + 3 < NT)      { asm volatile("s_waitcnt vmcnt(8)" ::: "memory"); }
            else if (t + 2 < NT) { asm volatile("s_waitcnt vmcnt(4)" ::: "memory"); }
            else                 { asm volatile("s_waitcnt vmcnt(0)" ::: "memory"); }
            __builtin_amdgcn_sched_barrier(0);
        }
        __builtin_amdgcn_s_barrier();
    }

    float bvals[4];
#pragma unroll
    for (int j = 0; j < 4; ++j)
        bvals[j] = bias[n0 + wc * 64 + j * 16 + (ln & 15)];
#pragma unroll
    for (int i = 0; i < 8; ++i)
#pragma unroll
        for (int j = 0; j < 4; ++j)
#pragma unroll
            for (int r = 0; r < 4; ++r) {
                int row = m0 + wr * 128 + i * 16 + (ln >> 4) * 4 + r;
                int col = n0 + wc * 64 + j * 16 + (ln & 15);
                float v = acc[i][j][r] + bvals[j];
                if constexpr (MODE == 0)
                    ((unsigned short*)Cout)[(size_t)row * N + col] = f2bf(v);
                else
                    ((float*)Cout)[(size_t)row * N + col] = v;
            }
}

// ---------------- 128x128 bf16 GEMM — K/V scatter only ----
static __device__ __forceinline__ void stage_tile(
    const unsigned short* __restrict__ G, int ldg, unsigned short* lds,
    int r0, int kt, int wv, int ln) {
    int rown = ln >> 2;
    int koff = (ln & 3) * 8;
#pragma unroll
    for (int r = 0; r < 2; ++r) {
        int cw = wv * 2 + r;
        const unsigned short* src =
            G + (size_t)(r0 + cw * 16 + rown) * ldg + kt + koff;
        __builtin_amdgcn_global_load_lds(
            (const __attribute__((address_space(1))) void*)src,
            (__attribute__((address_space(3))) void*)(lds + cw * 512),
            16, 0, 0);
    }
}

template <int MODE>
__global__ __launch_bounds__(256) void gemm_bt_kernel(
    const unsigned short* __restrict__ A, const unsigned short* __restrict__ Bt,
    const float* __restrict__ bias, void* __restrict__ Cout,
    int M, int N, int K) {
    __shared__ unsigned short As[128 * 32];
    __shared__ unsigned short Bs[128 * 32];
    const int tid = threadIdx.x, wv = tid >> 6, ln = tid & 63;
    const int numM = M >> 7, numN = N >> 7;
    int bid = blockIdx.x;
    const int nwg = numM * numN;
    if ((nwg & 7) == 0) { int cpx = nwg >> 3; bid = (bid & 7) * cpx + (bid >> 3); }
    const int nt = bid % numN, mt = bid / numN;
    const int m0 = mt << 7, n0 = nt << 7;
    const int wr = wv >> 1, wc = wv & 1;

    f32x4 acc[4][4] = {};
    for (int kt = 0; kt < K; kt += 32) {
        __syncthreads();
        stage_tile(A, K, As, m0, kt, wv, ln);
        stage_tile(Bt, K, Bs, n0, kt, wv, ln);
        __syncthreads();
        bf16x8 af[4], bfr[4];
#pragma unroll
        for (int i = 0; i < 4; ++i)
            af[i] = *(const bf16x8*)(As + (wr * 64 + i * 16 + (ln & 15)) * 32 +
                                     (ln >> 4) * 8);
#pragma unroll
        for (int j = 0; j < 4; ++j)
            bfr[j] = *(const bf16x8*)(Bs + (wc * 64 + j * 16 + (ln & 15)) * 32 +
                                      (ln >> 4) * 8);
#pragma unroll
        for (int i = 0; i < 4; ++i)
#pragma unroll
            for (int j = 0; j < 4; ++j)
                acc[i][j] = __builtin_amdgcn_mfma_f32_16x16x32_bf16(
                    af[i], bfr[j], acc[i][j], 0, 0, 0);
    }

    float bvals[4];
#pragma unroll
    for (int j = 0; j < 4; ++j)
        bvals[j] = bias[n0 + wc * 64 + j * 16 + (ln & 15)];

#pragma unroll
    for (int i = 0; i < 4; ++i) {
#pragma unroll
        for (int j = 0; j < 4; ++j) {
#pragma unroll
            for (int r = 0; r < 4; ++r) {
                int row = m0 + wr * 64 + i * 16 + (ln >> 4) * 4 + r;
                int col = n0 + wc * 64 + j * 16 + (ln & 15);
                float v = acc[i][j][r] + bvals[j];
                if (row < BB * MM) {
                    int bb = row / MM, m = row - bb * MM;
                    int hh = col >> 6, d = col & 63;
                    if constexpr (MODE == 2)
                        ((unsigned short*)Cout)[((size_t)(bb * NH + hh) * MPAD + m) * HD + d] = f2bf(v);
                    else
                        ((unsigned short*)Cout)[((size_t)(bb * NH + hh) * HD + d) * MPAD + m] = f2bf(v);
                }
            }
        }
    }
}

// ---------------- fused attention v3: 2 q-tiles/wave, V reg-prefetch ------
// wg = 4 waves = 128 q-rows of one head. Per wave 32 q-rows (2 tiles of 16).
// Slice m in [80,96) never valid (len<=77) -> statically dropped.
// K-slices and PV-chunks beyond len skipped via wg-uniform branches.
__global__ __launch_bounds__(256, 3) void attn_kernel(
    const unsigned short* __restrict__ Q, const unsigned short* __restrict__ Kw,
    const unsigned short* __restrict__ Vt, const int* __restrict__ lengths,
    unsigned short* __restrict__ Out) {
    const int bh = blockIdx.y;
    const int b = bh >> 4, h = bh & 15;
    const int q0 = blockIdx.x * 128;
    const int tid = threadIdx.x, wv = tid >> 6, ln = tid & 63;
    const int len = lengths[b];
    const int kscnt = (len + 31) >> 5; // 1..3 PV chunks of 32

    __shared__ unsigned short Ps[128][104]; // normalized P rows q, cols m

    const unsigned short* Ksrc = Kw + (size_t)bh * (MPAD * HD);
    const unsigned short* Vsrc = Vt + (size_t)bh * (HD * MPAD);

    // Q fragments: 2 q-tiles per wave
    bf16x8 aq[2][2];
#pragma unroll
    for (int qi = 0; qi < 2; ++qi) {
        const int qr = q0 + wv * 32 + qi * 16 + (ln & 15);
        const unsigned short* qptr =
            Q + (size_t)(b * NN + qr) * EMB + h * HD + (ln >> 4) * 8;
        aq[qi][0] = *(const bf16x8*)(qptr);
        aq[qi][1] = *(const bf16x8*)(qptr + 32);
    }

    // V prefetch into registers (independent of QK^T -> latency hidden)
    bf16x8 vf[3][4];
#pragma unroll
    for (int j = 0; j < 4; ++j)
        vf[0][j] = *(const bf16x8*)(Vsrc + (j * 16 + (ln & 15)) * MPAD +
                                    (ln >> 4) * 8);
    if (kscnt > 1) {
#pragma unroll
        for (int j = 0; j < 4; ++j)
            vf[1][j] = *(const bf16x8*)(Vsrc + (j * 16 + (ln & 15)) * MPAD + 32 +
                                        (ln >> 4) * 8);
    }
    if (kscnt > 2) {
#pragma unroll
        for (int j = 0; j < 4; ++j)
            vf[2][j] = *(const bf16x8*)(Vsrc + (j * 16 + (ln & 15)) * MPAD + 64 +
                                        (ln >> 4) * 8);
    }

    // S = Q K^T over 5 slices (80 cols); skip slices entirely beyond len
    f32x4 s[2][5] = {};
#pragma unroll
    for (int t = 0; t < 5; ++t) {
        if (t * 16 < len) {
            const unsigned short* kp =
                Ksrc + (t * 16 + (ln & 15)) * HD + (ln >> 4) * 8;
            bf16x8 k0 = *(const bf16x8*)(kp);
            bf16x8 k1 = *(const bf16x8*)(kp + 32);
#pragma unroll
            for (int qi = 0; qi < 2; ++qi) {
                s[qi][t] = __builtin_amdgcn_mfma_f32_16x16x32_bf16(
                    aq[qi][0], k0, s[qi][t], 0, 0, 0);
                s[qi][t] = __builtin_amdgcn_mfma_f32_16x16x32_bf16(
                    aq[qi][1], k1, s[qi][t], 0, 0, 0);
            }
        }
    }

    // masked softmax; S: row q=(ln>>4)*4+r, col m=t*16+(ln&15)
    const float scale = 0.125f;
    float mx[2][4], sum[2][4];
#pragma unroll
    for (int qi = 0; qi < 2; ++qi)
#pragma unroll
        for (int r = 0; r < 4; ++r) { mx[qi][r] = -1e30f; sum[qi][r] = 0.f; }
#pragma unroll
    for (int t = 0; t < 5; ++t) {
        int m = t * 16 + (ln & 15);
        bool valid = m < len;
#pragma unroll
        for (int qi = 0; qi < 2; ++qi)
#pragma unroll
            for (int r = 0; r < 4; ++r) {
                float v = valid ? s[qi][t][r] * scale : -1e30f;
                s[qi][t][r] = v;
                mx[qi][r] = fmaxf(mx[qi][r], v);
            }
    }
#pragma unroll
    for (int d = 1; d < 16; d <<= 1)
#pragma unroll
        for (int qi = 0; qi < 2; ++qi)
#pragma unroll
            for (int r = 0; r < 4; ++r)
                mx[qi][r] = fmaxf(mx[qi][r], __shfl_xor(mx[qi][r], d, 64));
#pragma unroll
    for (int t = 0; t < 5; ++t)
#pragma unroll
        for (int qi = 0; qi < 2; ++qi)
#pragma unroll
            for (int r = 0; r < 4; ++r) {
                float p = __expf(s[qi][t][r] - mx[qi][r]);
                s[qi][t][r] = p;
                sum[qi][r] += p;
            }
#pragma unroll
    for (int d = 1; d < 16; d <<= 1)
#pragma unroll
        for (int qi = 0; qi < 2; ++qi)
#pragma unroll
            for (int r = 0; r < 4; ++r)
                sum[qi][r] += __shfl_xor(sum[qi][r], d, 64);

    float rinv[2][4];
#pragma unroll
    for (int qi = 0; qi < 2; ++qi)
#pragma unroll
        for (int r = 0; r < 4; ++r) rinv[qi][r] = 1.0f / sum[qi][r];

    // write normalized P; slice 5 (m in [80,96)) = 0 for PV chunk ks=2.
    // Same-wave ds_write -> ds_read, own rows only: no barrier needed.
#pragma unroll
    for (int t = 0; t < 6; ++t)
#pragma unroll
        for (int qi = 0; qi < 2; ++qi)
#pragma unroll
            for (int r = 0; r < 4; ++r) {
                int row = wv * 32 + qi * 16 + (ln >> 4) * 4 + r;
                float v = (t < 5) ? s[qi][t][r] * rinv[qi][r] : 0.0f;
                Ps[row][t * 16 + (ln & 15)] = f2bf(v);
            }

    // O^T = V P^T (swapped): o[qi][j] = mfma(vf, pf) -> 4 consecutive d/lane
    f32x4 o[2][4] = {};
    for (int ks = 0; ks < kscnt; ++ks) {
#pragma unroll
        for (int qi = 0; qi < 2; ++qi) {
            bf16x8 pf = *(const bf16x8*)(&Ps[wv * 32 + qi * 16 + (ln & 15)]
                                            [ks * 32 + (ln >> 4) * 8]);
#pragma unroll
            for (int j = 0; j < 4; ++j)
                o[qi][j] = __builtin_amdgcn_mfma_f32_16x16x32_bf16(
                    vf[ks][j], pf, o[qi][j], 0, 0, 0);
        }
    }

    // packed 8B stores: 4 consecutive d per lane
#pragma unroll
    for (int qi = 0; qi < 2; ++qi) {
        const int qrow = q0 + wv * 32 + qi * 16 + (ln & 15);
        unsigned short* obase =
            Out + (size_t)(b * NN + qrow) * EMB + h * HD + (ln >> 4) * 4;
#pragma unroll
        for (int j = 0; j < 4; ++j) {
            union { unsigned short u[4]; unsigned long long ll; } pk;
#pragma unroll
            for (int r = 0; r < 4; ++r) pk.u[r] = f2bf(o[qi][j][r]);
            *(unsigned long long*)(obase + j * 16) = pk.ll;
        }
    }
}

// ---------------- launch ----------------
extern "C" void kernel_launch(void* const* d_in, const int* in_sizes, int n_in,
                              void* d_out, int out_size, void* d_ws, size_t ws_size,
                              hipStream_t stream) {
    const float* x    = (const float*)d_in[0];
    const float* ctx  = (const float*)d_in[1];
    const unsigned char* cmask = (const unsigned char*)d_in[2];
    const float* Wq = (const float*)d_in[3];
    const float* bq = (const float*)d_in[4];
    const float* Wk = (const float*)d_in[5];
    const float* bk = (const float*)d_in[6];
    const float* Wv = (const float*)d_in[7];
    const float* bv = (const float*)d_in[8];
    const float* Wo = (const float*)d_in[9];
    const float* bo = (const float*)d_in[10];

    char* ws = (char*)d_ws;
    unsigned short* Xbf   = (unsigned short*)(ws);              // 64 MiB; reused as attn_out
    unsigned short* Wq_t  = (unsigned short*)(ws + 67108864);   // 2 MiB
    unsigned short* Wo_t  = (unsigned short*)(ws + 69206016);   // 2 MiB
    unsigned short* Wk_t  = (unsigned short*)(ws + 71303168);   // 1.5 MiB
    unsigned short* Wv_t  = (unsigned short*)(ws + 72876032);   // 1.5 MiB
    unsigned short* Cbf   = (unsigned short*)(ws + 74448896);   // 640x768 bf16
    unsigned short* Kw    = (unsigned short*)(ws + 75431936);   // 128x96x64 bf16
    unsigned short* Vtw   = (unsigned short*)(ws + 77004800);   // 128x64x96 bf16
    int* lengths          = (int*)(ws + 78577664);
    unsigned short* Qb    = (unsigned short*)d_out;             // 64 MiB scratch

    mask_lengths_kernel<<<1, 64, 0, stream>>>(cmask, lengths);
    cast_f32_to_bf16<<<2048, 256, 0, stream>>>(x, Xbf, (BB * NN * EMB) / 8);
    cast_ctx_kernel<<<240, 256, 0, stream>>>(ctx, Cbf);
    TPtrs tp;
    tp.src[0] = Wq; tp.src[1] = Wo; tp.src[2] = Wk; tp.src[3] = Wv;
    tp.dst[0] = Wq_t; tp.dst[1] = Wo_t; tp.dst[2] = Wk_t; tp.dst[3] = Wv_t;
    transpose4_kernel<<<dim3(32, 32, 4), dim3(32, 8), 0, stream>>>(tp);
    hipMemsetAsync(Kw, 0, 2 * 1572864, stream); // zero K + V^T padded buffers

    gemm256_kernel<0><<<512, 512, 0, stream>>>(Xbf, Wq_t, bq, Qb, 32768, 1024, 1024);
    gemm_bt_kernel<2><<<40, 256, 0, stream>>>(Cbf, Wk_t, bk, Kw, 640, 1024, 768);
    gemm_bt_kernel<3><<<40, 256, 0, stream>>>(Cbf, Wv_t, bv, Vtw, 640, 1024, 768);

    attn_kernel<<<dim3(32, 128), 256, 0, stream>>>(Qb, Kw, Vtw, lengths, Xbf);

    gemm256_kernel<1><<<512, 512, 0, stream>>>(Xbf, Wo_t, bo, d_out, 32768, 1024, 1024);
}